// Round 24
// baseline (602.290 us; speedup 1.0000x reference)
//
#include <hip/hip_runtime.h>
#include <hip/hip_bf16.h>
#include <math.h>

#define BB 8
#define SS 512
#define DDIM 512
#define HH 8
#define DFFV 2048
#define NLAYER 6
#define EPSV 1e-5f
#define WQS 0.180336880f  // 0.125 * log2(e)

typedef __attribute__((ext_vector_type(8))) short bf16x8;
typedef __attribute__((ext_vector_type(4))) float f32x4;

static __device__ __forceinline__ ushort f2bf(float f) {
  union { float f; unsigned u; } uf; uf.f = f;
  unsigned u = uf.u;
  unsigned r = (u + 0x7fffu + ((u >> 16) & 1u)) >> 16;
  return (ushort)r;
}
static __device__ __forceinline__ float bf2f(ushort h) {
  union { unsigned u; float f; } x;
  x.u = ((unsigned)h) << 16;
  return x.f;
}

static __device__ __forceinline__ void gload_lds16(const void* g, void* l) {
  __builtin_amdgcn_global_load_lds(
      (const __attribute__((address_space(1))) void*)g,
      (__attribute__((address_space(3))) void*)l, 16, 0, 0);
}

// ---------------- fused prep: embed+PE, enc cast, bias packing ------------
__global__ __launch_bounds__(256) void prep_kernel(
    const int* __restrict__ idx, const float* __restrict__ emb,
    const float* __restrict__ enc, const float* __restrict__ bq,
    const float* __restrict__ bk, const float* __restrict__ bv,
    const float* __restrict__ bkc, const float* __restrict__ bvc,
    const float* __restrict__ bqc, ushort* __restrict__ xb,
    ushort* __restrict__ encb, float* __restrict__ qkvb,
    float* __restrict__ ckvb, float* __restrict__ cqb) {
  int gid = blockIdx.x * 256 + threadIdx.x;  // 0..524287
  {
    int t0 = gid * 4;
    int bs = t0 >> 9;
    int s = bs & (SS - 1);
    int tok = idx[bs];
    ushort4 o;
    float vv[4];
#pragma unroll
    for (int e = 0; e < 4; e++) {
      int d = (t0 + e) & (DDIM - 1);
      int i2 = d & ~1;
      float ang = (float)s * powf(10000.0f, -((float)i2) / (float)DDIM);
      float pe = (d & 1) ? cosf(ang) : sinf(ang);
      vv[e] = emb[(size_t)tok * DDIM + d] + pe;
    }
    o.x = f2bf(vv[0]); o.y = f2bf(vv[1]); o.z = f2bf(vv[2]); o.w = f2bf(vv[3]);
    *reinterpret_cast<ushort4*>(xb + t0) = o;
  }
  {
    float4 v = reinterpret_cast<const float4*>(enc)[gid];
    ushort4 o;
    o.x = f2bf(v.x); o.y = f2bf(v.y); o.z = f2bf(v.z); o.w = f2bf(v.w);
    reinterpret_cast<ushort4*>(encb)[gid] = o;
  }
  int t = gid;
  if (t < NLAYER * 1536) {
    int l = t / 1536, n = t % 1536;
    float v = n < 512 ? bq[l * 512 + n] * WQS
                      : (n < 1024 ? bk[l * 512 + n - 512] : bv[l * 512 + n - 1024]);
    qkvb[t] = v;
  }
  if (t < NLAYER * 1024) {
    int l = t / 1024, n = t % 1024;
    ckvb[t] = n < 512 ? bkc[l * 512 + n] : bvc[l * 512 + n - 512];
  }
  if (t < NLAYER * 512) cqb[t] = bqc[t] * WQS;
}

// ---------------- merged 6-way head-weight transpose (512x64 each) --------
__global__ __launch_bounds__(256) void wtrans6_kernel(
    const float* __restrict__ qs, const float* __restrict__ ks,
    const float* __restrict__ vs, const float* __restrict__ qc,
    const float* __restrict__ kc, const float* __restrict__ vc,
    ushort* __restrict__ wqkv, ushort* __restrict__ wqc,
    ushort* __restrict__ wckv) {
  __shared__ float t[32][33];
  int z = blockIdx.z;        // 0..287
  int job = z / 48, zz = z % 48;
  const float* in; ushort* out; size_t zl; float scale;
  switch (job) {
    case 0: in = qs; out = wqkv;           zl = 786432; scale = WQS; break;
    case 1: in = ks; out = wqkv + 262144;  zl = 786432; scale = 1.f; break;
    case 2: in = vs; out = wqkv + 524288;  zl = 786432; scale = 1.f; break;
    case 3: in = qc; out = wqc;            zl = 262144; scale = WQS; break;
    case 4: in = kc; out = wckv;           zl = 524288; scale = 1.f; break;
    default: in = vc; out = wckv + 262144; zl = 524288; scale = 1.f; break;
  }
  int l = zz >> 3, hh = zz & 7;
  const float* ip = in + (size_t)zz * 512 * 64;
  ushort* op = out + (size_t)l * zl + (size_t)hh * 512 * 64;
  int j = threadIdx.x & 31, i0 = threadIdx.x >> 5;
  int r0 = blockIdx.y * 32, c0 = blockIdx.x * 32;
#pragma unroll
  for (int p = 0; p < 4; p++) {
    int r = r0 + i0 + p * 8;
    t[i0 + p * 8][j] = ip[(size_t)r * 64 + c0 + j];
  }
  __syncthreads();
#pragma unroll
  for (int p = 0; p < 4; p++) {
    int cc = c0 + i0 + p * 8;
    op[(size_t)cc * 512 + r0 + j] = f2bf(t[j][i0 + p * 8] * scale);
  }
}

// ---------------- merged FF weight transpose ------------------------------
__global__ __launch_bounds__(256) void wtransff_kernel(
    const float* __restrict__ W1, const float* __restrict__ W2,
    ushort* __restrict__ w1t, ushort* __restrict__ w2t) {
  __shared__ float t[32][33];
  int z = blockIdx.z;
  int isW2 = z >= NLAYER;
  int l = isW2 ? z - NLAYER : z;
  int R = isW2 ? 2048 : 512;
  int C = isW2 ? 512 : 2048;
  int r0, c0;
  if (!isW2) { c0 = blockIdx.x * 32; r0 = blockIdx.y * 32; }
  else       { r0 = blockIdx.x * 32; c0 = blockIdx.y * 32; }
  const float* ip = (isW2 ? W2 : W1) + (size_t)l * 1048576;
  ushort* op = (isW2 ? w2t : w1t) + (size_t)l * 1048576;
  int j = threadIdx.x & 31, i0 = threadIdx.x >> 5;
#pragma unroll
  for (int p = 0; p < 4; p++) {
    int r = r0 + i0 + p * 8;
    t[i0 + p * 8][j] = ip[(size_t)r * C + c0 + j];
  }
  __syncthreads();
#pragma unroll
  for (int p = 0; p < 4; p++) {
    int cc = c0 + i0 + p * 8;
    op[(size_t)cc * R + r0 + j] = f2bf(t[j][i0 + p * 8]);
  }
}

// ---------------- bf16 MFMA GEMM, 2-phase pipelined (counted vmcnt) -------
template <int BM, int BN, int RELU, int OUTBF, int NTV, int LGP, int SPLITK,
          int SWZ>
__global__ __launch_bounds__(256) void gemm_mfma(
    const ushort* __restrict__ A, const ushort* __restrict__ Bw,
    const float* __restrict__ bias, float* __restrict__ Cf,
    ushort* __restrict__ Cb, ushort* __restrict__ vt, int M, int N, int K) {
  constexpr int WM = BM / 64;
  constexpr int WN = 4 / WM;
  constexpr int W = BN / WN;
  constexpr int AF = 4;
  constexpr int BF = W / 16;
  constexpr int GA = BM * 8;
  constexpr int GPT = (BM + BN) * 8 / 256;
  __shared__ __align__(16) ushort lds_s[2][(BM + BN) * 64];
  int bn, bm;
  if (SWZ == 1) {
    int nwg = gridDim.x * gridDim.y;
    int wg = blockIdx.y * gridDim.x + blockIdx.x;
    int cpx = nwg >> 3;
    int swz = (wg & 7) * cpx + (wg >> 3);
    bn = (swz % gridDim.x) * BN;
    bm = (swz / gridDim.x) * BM;
  } else {
    bn = blockIdx.x * BN;
    bm = blockIdx.y * BM;
  }
  int kz = (SPLITK > 1) ? blockIdx.z : 0;
  int Keff = K / SPLITK;
  int kbase = kz * Keff;
  int tid = threadIdx.x, lane = tid & 63, w = tid >> 6;
  int wm = w / WN, wn = w % WN;
  int c = lane & 15, g16 = lane >> 4;
  f32x4 acc[AF][BF] = {};

  auto STAGE = [&](int k0, int bufi) {
#pragma unroll
    for (int i = 0; i < GPT; i++) {
      int gidx = i * 256 + tid;
      int gbase = (i * 4 + w) * 64;
      const ushort* src;
      if (gidx < GA) {
        int row = gidx >> 3, dg = gidx & 7;
        src = A + (size_t)(bm + row) * K + kbase + k0 + ((dg ^ (row & 7)) << 3);
      } else {
        int bidx = gidx - GA;
        int row = bidx >> 3, dg = bidx & 7;
        src = Bw + (size_t)(bn + row) * K + kbase + k0 + ((dg ^ (row & 7)) << 3);
      }
      gload_lds16(src, (void*)((char*)(&lds_s[bufi][0]) + gbase * 16));
    }
  };

  int nk = Keff >> 6;
  STAGE(0, 0);
  for (int kt = 0; kt < nk; kt++) {
    int cur = kt & 1;
    if (kt + 1 < nk) {
      STAGE((kt + 1) << 6, cur ^ 1);
      asm volatile("s_waitcnt vmcnt(%0)" ::"n"(GPT) : "memory");
    } else {
      asm volatile("s_waitcnt vmcnt(0)" ::: "memory");
    }
    __builtin_amdgcn_s_barrier();
    __builtin_amdgcn_sched_barrier(0);
    const ushort* Alds = &lds_s[cur][0];
    const ushort* Blds = &lds_s[cur][BM * 64];
#pragma unroll
    for (int ks = 0; ks < 2; ks++) {
      int g = ks * 4 + g16;
      bf16x8 a[AF], b[BF];
#pragma unroll
      for (int i = 0; i < AF; i++) {
        int R = wm * 64 + i * 16 + c;
        a[i] = *(const bf16x8*)(Alds + R * 64 + ((g ^ (R & 7)) << 3));
      }
#pragma unroll
      for (int j = 0; j < BF; j++) {
        int Rb = wn * W + j * 16 + c;
        b[j] = *(const bf16x8*)(Blds + Rb * 64 + ((g ^ (Rb & 7)) << 3));
      }
#pragma unroll
      for (int i = 0; i < AF; i++)
#pragma unroll
        for (int j = 0; j < BF; j++)
          acc[i][j] = __builtin_amdgcn_mfma_f32_16x16x32_bf16(a[i], b[j],
                                                              acc[i][j], 0, 0, 0);
    }
    __builtin_amdgcn_sched_barrier(0);
    __builtin_amdgcn_s_barrier();
  }
  int rb = g16 * 4;
#pragma unroll
  for (int j = 0; j < BF; j++) {
    int col = bn + wn * W + j * 16 + c;
    float bv = (SPLITK > 1 && kz != 0) ? 0.0f : bias[col];
    int cc = LGP ? (col & ((1 << LGP) - 1)) : col;
    int lp = LGP ? (col >> LGP) : 0;
    if (NTV > 0 && cc >= NTV) {
      int hh = (cc - NTV) >> 6, dv = col & 63;
      ushort* vtl = vt + (size_t)lp * 2097152;
#pragma unroll
      for (int i = 0; i < AF; i++) {
        int row = bm + wm * 64 + i * 16 + rb;
        int b_ = row >> 9, s_ = row & 511;
        ushort4 o4;
        o4.x = f2bf(acc[i][j][0] + bv);
        o4.y = f2bf(acc[i][j][1] + bv);
        o4.z = f2bf(acc[i][j][2] + bv);
        o4.w = f2bf(acc[i][j][3] + bv);
        *reinterpret_cast<ushort4*>(
            vtl + ((size_t)(b_ * 8 + hh) * 64 + dv) * 512 + s_) = o4;
      }
    } else {
#pragma unroll
      for (int i = 0; i < AF; i++) {
#pragma unroll
        for (int qq = 0; qq < 4; qq++) {
          int row = bm + wm * 64 + i * 16 + rb + qq;
          float v = acc[i][j][qq] + bv;
          if (RELU) v = fmaxf(v, 0.0f);
          if (OUTBF)
            Cb[(size_t)kz * M * N + (size_t)row * N + col] = f2bf(v);
          else
            Cf[(size_t)kz * M * N + (size_t)row * N + col] = v;
        }
      }
    }
  }
}

// ---------------- MFMA flash attention (swapped QK^T, lane-local softmax) --
// QSUM=1: q points at two bf16 split-K partials (stride 4096*512 elements);
// the prologue sums them (same double-rounding scheme as FF2 partials).
template <int MASKED, int NW, int QSUM>
__global__ __launch_bounds__(NW * 64) void attn_mfma(
    const ushort* __restrict__ q, int qstr, const ushort* __restrict__ k,
    int kstr, const ushort* __restrict__ vt, ushort* __restrict__ out) {
  __shared__ __align__(16) char lds[32768 + NW * 2048];
  int h = blockIdx.y, b = blockIdx.z;
  int qc = blockIdx.x;
  if (MASKED && (b & 4)) qc = gridDim.x - 1 - qc;  // causal balance flip
  int q0 = qc * (NW * 16);
  int tid = threadIdx.x, lane = tid & 63, w = tid >> 6;
  int c = lane & 15, g16 = lane >> 4, rb = g16 * 4;

  bf16x8 qa[2];
#pragma unroll
  for (int ks = 0; ks < 2; ks++) {
    const ushort* qp = q + (size_t)(b * SS + q0 + 16 * w + c) * qstr + h * 64 +
                       ks * 32 + g16 * 8;
    if (QSUM) {
      bf16x8 a0 = *(const bf16x8*)qp;
      bf16x8 a1 = *(const bf16x8*)(qp + 2097152);  // + 4096*512
#pragma unroll
      for (int e = 0; e < 8; e++)
        qa[ks][e] = (short)f2bf(bf2f((ushort)a0[e]) + bf2f((ushort)a1[e]));
    } else {
      qa[ks] = *(const bf16x8*)qp;
    }
  }
  f32x4 o[4] = {};
  float mq = -1e30f, lq = 0.f;

  int nt = MASKED ? (q0 >> 6) + 1 : 8;
  int pbase = 32768 + w * 2048;

  constexpr int GPTK = 512 / (NW * 64);
  bf16x8 rk[GPTK], rv[GPTK];
  const ushort* vbase = vt + ((size_t)(b * 8 + h) * 64) * 512;
  auto LOADT = [&](int kv0) {
#pragma unroll
    for (int i = 0; i < GPTK; i++) {
      int idx = tid + i * (NW * 64);
      int row = idx >> 3, gw = idx & 7;
      rk[i] = *(const bf16x8*)(k + (size_t)(b * SS + kv0 + row) * kstr +
                               h * 64 + gw * 8);
      rv[i] = *(const bf16x8*)(vbase + (size_t)row * 512 + kv0 + gw * 8);
    }
  };
  auto WRT = [&](int bufi) {
    char* p = lds + bufi * 16384;
#pragma unroll
    for (int i = 0; i < GPTK; i++) {
      int idx = tid + i * (NW * 64);
      int row = idx >> 3, gw = idx & 7;
      *(bf16x8*)(p + row * 128 + ((gw ^ (row & 7)) << 4)) = rk[i];
      *(bf16x8*)(p + 8192 + row * 128 + ((gw ^ (row & 7)) << 4)) = rv[i];
    }
  };
  LOADT(0);
  WRT(0);
  for (int t = 0; t < nt; t++) {
    if (t + 1 < nt) LOADT((t + 1) * 64);
    __syncthreads();
    char* kb_ = lds + (t & 1) * 16384;
    char* vb_ = kb_ + 8192;
    f32x4 sp[4] = {};
    __builtin_amdgcn_s_setprio(1);
#pragma unroll
    for (int ks = 0; ks < 2; ks++) {
      int g = ks * 4 + g16;
#pragma unroll
      for (int f = 0; f < 4; f++) {
        int row = f * 16 + c;
        bf16x8 k8 = *(bf16x8*)(kb_ + row * 128 + ((g ^ (row & 7)) << 4));
        sp[f] = __builtin_amdgcn_mfma_f32_16x16x32_bf16(k8, qa[ks], sp[f], 0, 0, 0);
      }
    }
    __builtin_amdgcn_s_setprio(0);
    if (MASKED && t == nt - 1) {
      int ql = 16 * w + c;
#pragma unroll
      for (int f = 0; f < 4; f++)
#pragma unroll
        for (int j = 0; j < 4; j++)
          sp[f][j] += (f * 16 + rb + j) <= ql ? 0.0f : -1e9f;
    }
    float tmax = -1e30f;
#pragma unroll
    for (int f = 0; f < 4; f++)
#pragma unroll
      for (int j = 0; j < 4; j++) tmax = fmaxf(tmax, sp[f][j]);
    tmax = fmaxf(tmax, __shfl_xor(tmax, 16));
    tmax = fmaxf(tmax, __shfl_xor(tmax, 32));
    if (!__all(tmax <= mq + 4.0f)) {
      float mn = fmaxf(mq, tmax);
      float scq = exp2f(mq - mn);
      mq = mn;
      lq *= scq;
      int sb = lane & 48;
#pragma unroll
      for (int j = 0; j < 4; j++) {
        float scj = __shfl(scq, sb | (rb + j));
        o[0][j] *= scj; o[1][j] *= scj; o[2][j] *= scj; o[3][j] *= scj;
      }
    }
    float psum = 0.f;
#pragma unroll
    for (int f = 0; f < 4; f++)
#pragma unroll
      for (int j = 0; j < 4; j++) {
        float pv = exp2f(sp[f][j] - mq);
        sp[f][j] = pv;
        psum += pv;
      }
    psum += __shfl_xor(psum, 16);
    psum += __shfl_xor(psum, 32);
    lq += psum;
#pragma unroll
    for (int f = 0; f < 4; f++) {
      int kv0 = f * 16 + rb;
      ushort4 pk;
      pk.x = f2bf(sp[f][0]); pk.y = f2bf(sp[f][1]);
      pk.z = f2bf(sp[f][2]); pk.w = f2bf(sp[f][3]);
      int gg = kv0 >> 3, off = (kv0 & 7) * 2;
      *(ushort4*)(lds + pbase + c * 128 + ((gg ^ (c & 7)) << 4) + off) = pk;
    }
    __builtin_amdgcn_s_setprio(1);
#pragma unroll
    for (int ks2 = 0; ks2 < 2; ks2++) {
      int g = ks2 * 4 + g16;
      bf16x8 pa = *(bf16x8*)(lds + pbase + c * 128 + ((g ^ (c & 7)) << 4));
#pragma unroll
      for (int f = 0; f < 4; f++) {
        int row = f * 16 + c;
        bf16x8 v8 = *(bf16x8*)(vb_ + row * 128 + ((g ^ (row & 7)) << 4));
        o[f] = __builtin_amdgcn_mfma_f32_16x16x32_bf16(pa, v8, o[f], 0, 0, 0);
      }
    }
    __builtin_amdgcn_s_setprio(0);
    if (t + 1 < nt) WRT((t + 1) & 1);
  }
  float invq = 1.0f / lq;
  int sb = lane & 48;
#pragma unroll
  for (int j = 0; j < 4; j++) {
    float invj = __shfl(invq, sb | (rb + j));
    size_t rowo = (size_t)(b * SS + q0 + 16 * w + rb + j) * 512 + h * 64;
#pragma unroll
    for (int f = 0; f < 4; f++)
      out[rowo + f * 16 + c] = f2bf(o[f][j] * invj);
  }
}

// ---------------- residual add + LayerNorm (bf16 residual, wave/row) ------
// Y2=0: y = bf16 yb.  Y2=2: y = bf16 yb + bf16 yb1 (split-K bf16 partials).
// xf != nullptr (final layer): write fp32 out only; xb store skipped (dead).
template <int Y2>
__global__ __launch_bounds__(256) void add_ln_kernel(
    ushort* __restrict__ xb, const ushort* __restrict__ yb,
    const ushort* __restrict__ yb1, const float* __restrict__ g,
    const float* __restrict__ bta, float* __restrict__ xf) {
  int row = blockIdx.x * 4 + (threadIdx.x >> 6);
  int lane = threadIdx.x & 63;
  int base = row * DDIM + lane * 8;
  bf16x8 xv = *reinterpret_cast<const bf16x8*>(xb + base);
  float v[8];
  bf16x8 yv = *reinterpret_cast<const bf16x8*>(yb + base);
  if (Y2 == 2) {
    bf16x8 y2v = *reinterpret_cast<const bf16x8*>(yb1 + base);
#pragma unroll
    for (int i = 0; i < 8; i++)
      v[i] = bf2f((ushort)xv[i]) + bf2f((ushort)yv[i]) + bf2f((ushort)y2v[i]);
  } else {
#pragma unroll
    for (int i = 0; i < 8; i++)
      v[i] = bf2f((ushort)xv[i]) + bf2f((ushort)yv[i]);
  }
  float s = 0.f;
#pragma unroll
  for (int i = 0; i < 8; i++) s += v[i];
#pragma unroll
  for (int off = 32; off > 0; off >>= 1) s += __shfl_xor(s, off);
  float mean = s * (1.0f / DDIM);
  float t2 = 0.f;
#pragma unroll
  for (int i = 0; i < 8; i++) {
    v[i] -= mean;
    t2 += v[i] * v[i];
  }
#pragma unroll
  for (int off = 32; off > 0; off >>= 1) t2 += __shfl_xor(t2, off);
  float rs = rsqrtf(t2 * (1.0f / DDIM) + EPSV);
  int cidx = lane * 8;
  float4 g0 = *reinterpret_cast<const float4*>(g + cidx);
  float4 g1 = *reinterpret_cast<const float4*>(g + cidx + 4);
  float4 b0 = *reinterpret_cast<const float4*>(bta + cidx);
  float4 b1 = *reinterpret_cast<const float4*>(bta + cidx + 4);
  float o[8];
  o[0] = v[0] * rs * g0.x + b0.x; o[1] = v[1] * rs * g0.y + b0.y;
  o[2] = v[2] * rs * g0.z + b0.z; o[3] = v[3] * rs * g0.w + b0.w;
  o[4] = v[4] * rs * g1.x + b1.x; o[5] = v[5] * rs * g1.y + b1.y;
  o[6] = v[6] * rs * g1.z + b1.z; o[7] = v[7] * rs * g1.w + b1.w;
  if (xf) {
    float4 w0 = {o[0], o[1], o[2], o[3]}, w1 = {o[4], o[5], o[6], o[7]};
    *reinterpret_cast<float4*>(xf + base) = w0;
    *reinterpret_cast<float4*>(xf + base + 4) = w1;
  } else {
    bf16x8 ob;
#pragma unroll
    for (int i = 0; i < 8; i++) ob[i] = (short)f2bf(o[i]);
    *reinterpret_cast<bf16x8*>(xb + base) = ob;
  }
}

// ---------------- orchestration ----------------
extern "C" void kernel_launch(void* const* d_in, const int* in_sizes, int n_in,
                              void* d_out, int out_size, void* d_ws,
                              size_t ws_size, hipStream_t stream) {
  const int* dec = (const int*)d_in[0];
  const float* enc = (const float*)d_in[1];
  const float* emb = (const float*)d_in[4];
  const float* Wq_s = (const float*)d_in[5];
  const float* Wk_s = (const float*)d_in[6];
  const float* Wv_s = (const float*)d_in[7];
  const float* bq_s = (const float*)d_in[8];
  const float* bk_s = (const float*)d_in[9];
  const float* bv_s = (const float*)d_in[10];
  const float* Wq_c = (const float*)d_in[11];
  const float* Wk_c = (const float*)d_in[12];
  const float* Wv_c = (const float*)d_in[13];
  const float* bq_c = (const float*)d_in[14];
  const float* bk_c = (const float*)d_in[15];
  const float* bv_c = (const float*)d_in[16];
  const float* W1 = (const float*)d_in[17];
  const float* b1 = (const float*)d_in[18];
  const float* W2 = (const float*)d_in[19];
  const float* b2 = (const float*)d_in[20];
  const float* ln1_g = (const float*)d_in[21];
  const float* ln1_b = (const float*)d_in[22];
  const float* ln2_g = (const float*)d_in[23];
  const float* ln2_b = (const float*)d_in[24];

  char* ws = (char*)d_ws;
  ushort* wqkv = (ushort*)(ws + 0);
  ushort* wqc = (ushort*)(ws + 9437184ull);
  ushort* wckv = (ushort*)(ws + 12582912ull);
  ushort* w1t = (ushort*)(ws + 18874368ull);
  ushort* w2t = (ushort*)(ws + 31457280ull);
  ushort* encb = (ushort*)(ws + 44040192ull);
  ushort* xb = (ushort*)(ws + 48234496ull);
  ushort* tmpb = (ushort*)(ws + 52428800ull);
  ushort* ff2p = (ushort*)(ws + 56623104ull);   // 2 x 4MB bf16 partials
  ushort* qkvbuf = (ushort*)(ws + 73400320ull);
  ushort* cq = (ushort*)(ws + 73400320ull);     // [2][4096][512] split-K parts
  ushort* ff1b = (ushort*)(ws + 73400320ull);
  ushort* vt = (ushort*)(ws + 85983232ull);
  float* qkvbias = (float*)(ws + 90177536ull);
  float* ckvbias = (float*)(ws + 90214400ull);
  ushort* ckvbuf = (ushort*)(ws + 90238976ull);
  ushort* vtc = (ushort*)(ws + 140570624ull);
  float* cqbias = (float*)(ws + 165736448ull);

  const int M = BB * SS;  // 4096
  dim3 g256(256);

  prep_kernel<<<dim3(2048), g256, 0, stream>>>(dec, emb, enc, bq_s, bk_s, bv_s,
                                               bk_c, bv_c, bq_c, xb, encb,
                                               qkvbias, ckvbias, cqbias);
  wtrans6_kernel<<<dim3(2, 16, 288), g256, 0, stream>>>(
      Wq_s, Wk_s, Wv_s, Wq_c, Wk_c, Wv_c, wqkv, wqc, wckv);
  wtransff_kernel<<<dim3(64, 16, 12), g256, 0, stream>>>(W1, W2, w1t, w2t);

  // ---- hoisted cross K/V; plain block order (both XCD chunkings thrash) ---
  gemm_mfma<128, 128, 0, 1, 512, 10, 1, 0><<<dim3(48, 32), g256, 0, stream>>>(
      encb, wckv, ckvbias, nullptr, ckvbuf, vtc, M, 6144, 512);

  for (int l = 0; l < NLAYER; l++) {
    gemm_mfma<64, 128, 0, 1, 1024, 0, 1, 1><<<dim3(12, 64), g256, 0, stream>>>(
        xb, wqkv + (size_t)l * 786432, qkvbias + l * 1536, nullptr, qkvbuf, vt,
        M, 1536, 512);
    attn_mfma<1, 4, 0><<<dim3(8, 8, 8), g256, 0, stream>>>(
        qkvbuf, 1536, qkvbuf + 512, 1536, vt, tmpb);
    add_ln_kernel<0><<<dim3(M / 4), g256, 0, stream>>>(
        xb, tmpb, nullptr, ln1_g + l * 512, ln1_b + l * 512, nullptr);
    // cross-Q projection: split-K2 (512 blocks, 2/CU), bf16 partials summed
    // in the attention prologue (same scheme as FF2 partials)
    gemm_mfma<64, 128, 0, 1, 0, 0, 2, 1><<<dim3(4, 64, 2), g256, 0, stream>>>(
        xb, wqc + (size_t)l * 262144, cqbias + l * 512, nullptr, cq, nullptr,
        M, 512, 512);
    attn_mfma<0, 8, 1><<<dim3(4, 8, 8), dim3(512), 0, stream>>>(
        cq, 512, ckvbuf + l * 1024, 6144, vtc + (size_t)l * 2097152, tmpb);
    add_ln_kernel<0><<<dim3(M / 4), g256, 0, stream>>>(
        xb, tmpb, nullptr, ln2_g + l * 512, ln2_b + l * 512, nullptr);
    gemm_mfma<128, 128, 1, 1, 0, 0, 1, 1><<<dim3(16, 32), g256, 0, stream>>>(
        xb, w1t + (size_t)l * 1048576, b1 + l * DFFV, nullptr, ff1b, nullptr,
        M, DFFV, 512);
    gemm_mfma<64, 128, 0, 1, 0, 0, 2, 1><<<dim3(4, 64, 2), g256, 0, stream>>>(
        ff1b, w2t + (size_t)l * 1048576, b2 + l * 512, nullptr, ff2p, nullptr,
        M, 512, DFFV);
    add_ln_kernel<2><<<dim3(M / 4), g256, 0, stream>>>(
        xb, ff2p, ff2p + (size_t)M * 512, ln2_g + l * 512, ln2_b + l * 512,
        (l == NLAYER - 1) ? (float*)d_out : nullptr);
  }
}

// Round 25
// 600.542 us; speedup vs baseline: 1.0029x; 1.0029x over previous
//
#include <hip/hip_runtime.h>
#include <hip/hip_bf16.h>
#include <math.h>

#define BB 8
#define SS 512
#define DDIM 512
#define HH 8
#define DFFV 2048
#define NLAYER 6
#define EPSV 1e-5f
#define WQS 0.180336880f  // 0.125 * log2(e)

typedef __attribute__((ext_vector_type(8))) short bf16x8;
typedef __attribute__((ext_vector_type(4))) float f32x4;

static __device__ __forceinline__ ushort f2bf(float f) {
  union { float f; unsigned u; } uf; uf.f = f;
  unsigned u = uf.u;
  unsigned r = (u + 0x7fffu + ((u >> 16) & 1u)) >> 16;
  return (ushort)r;
}
static __device__ __forceinline__ float bf2f(ushort h) {
  union { unsigned u; float f; } x;
  x.u = ((unsigned)h) << 16;
  return x.f;
}

static __device__ __forceinline__ void gload_lds16(const void* g, void* l) {
  __builtin_amdgcn_global_load_lds(
      (const __attribute__((address_space(1))) void*)g,
      (__attribute__((address_space(3))) void*)l, 16, 0, 0);
}

// ---------------- fused prep: embed+PE, enc cast, bias packing ------------
__global__ __launch_bounds__(256) void prep_kernel(
    const int* __restrict__ idx, const float* __restrict__ emb,
    const float* __restrict__ enc, const float* __restrict__ bq,
    const float* __restrict__ bk, const float* __restrict__ bv,
    const float* __restrict__ bkc, const float* __restrict__ bvc,
    const float* __restrict__ bqc, ushort* __restrict__ xb,
    ushort* __restrict__ encb, float* __restrict__ qkvb,
    float* __restrict__ ckvb, float* __restrict__ cqb) {
  int gid = blockIdx.x * 256 + threadIdx.x;  // 0..524287
  {
    int t0 = gid * 4;
    int bs = t0 >> 9;
    int s = bs & (SS - 1);
    int tok = idx[bs];
    ushort4 o;
    float vv[4];
#pragma unroll
    for (int e = 0; e < 4; e++) {
      int d = (t0 + e) & (DDIM - 1);
      int i2 = d & ~1;
      float ang = (float)s * powf(10000.0f, -((float)i2) / (float)DDIM);
      float pe = (d & 1) ? cosf(ang) : sinf(ang);
      vv[e] = emb[(size_t)tok * DDIM + d] + pe;
    }
    o.x = f2bf(vv[0]); o.y = f2bf(vv[1]); o.z = f2bf(vv[2]); o.w = f2bf(vv[3]);
    *reinterpret_cast<ushort4*>(xb + t0) = o;
  }
  {
    float4 v = reinterpret_cast<const float4*>(enc)[gid];
    ushort4 o;
    o.x = f2bf(v.x); o.y = f2bf(v.y); o.z = f2bf(v.z); o.w = f2bf(v.w);
    reinterpret_cast<ushort4*>(encb)[gid] = o;
  }
  int t = gid;
  if (t < NLAYER * 1536) {
    int l = t / 1536, n = t % 1536;
    float v = n < 512 ? bq[l * 512 + n] * WQS
                      : (n < 1024 ? bk[l * 512 + n - 512] : bv[l * 512 + n - 1024]);
    qkvb[t] = v;
  }
  if (t < NLAYER * 1024) {
    int l = t / 1024, n = t % 1024;
    ckvb[t] = n < 512 ? bkc[l * 512 + n] : bvc[l * 512 + n - 512];
  }
  if (t < NLAYER * 512) cqb[t] = bqc[t] * WQS;
}

// ---------------- merged 6-way head-weight transpose (512x64 each) --------
__global__ __launch_bounds__(256) void wtrans6_kernel(
    const float* __restrict__ qs, const float* __restrict__ ks,
    const float* __restrict__ vs, const float* __restrict__ qc,
    const float* __restrict__ kc, const float* __restrict__ vc,
    ushort* __restrict__ wqkv, ushort* __restrict__ wqc,
    ushort* __restrict__ wckv) {
  __shared__ float t[32][33];
  int z = blockIdx.z;        // 0..287
  int job = z / 48, zz = z % 48;
  const float* in; ushort* out; size_t zl; float scale;
  switch (job) {
    case 0: in = qs; out = wqkv;           zl = 786432; scale = WQS; break;
    case 1: in = ks; out = wqkv + 262144;  zl = 786432; scale = 1.f; break;
    case 2: in = vs; out = wqkv + 524288;  zl = 786432; scale = 1.f; break;
    case 3: in = qc; out = wqc;            zl = 262144; scale = WQS; break;
    case 4: in = kc; out = wckv;           zl = 524288; scale = 1.f; break;
    default: in = vc; out = wckv + 262144; zl = 524288; scale = 1.f; break;
  }
  int l = zz >> 3, hh = zz & 7;
  const float* ip = in + (size_t)zz * 512 * 64;
  ushort* op = out + (size_t)l * zl + (size_t)hh * 512 * 64;
  int j = threadIdx.x & 31, i0 = threadIdx.x >> 5;
  int r0 = blockIdx.y * 32, c0 = blockIdx.x * 32;
#pragma unroll
  for (int p = 0; p < 4; p++) {
    int r = r0 + i0 + p * 8;
    t[i0 + p * 8][j] = ip[(size_t)r * 64 + c0 + j];
  }
  __syncthreads();
#pragma unroll
  for (int p = 0; p < 4; p++) {
    int cc = c0 + i0 + p * 8;
    op[(size_t)cc * 512 + r0 + j] = f2bf(t[j][i0 + p * 8] * scale);
  }
}

// ---------------- merged FF weight transpose ------------------------------
__global__ __launch_bounds__(256) void wtransff_kernel(
    const float* __restrict__ W1, const float* __restrict__ W2,
    ushort* __restrict__ w1t, ushort* __restrict__ w2t) {
  __shared__ float t[32][33];
  int z = blockIdx.z;
  int isW2 = z >= NLAYER;
  int l = isW2 ? z - NLAYER : z;
  int R = isW2 ? 2048 : 512;
  int C = isW2 ? 512 : 2048;
  int r0, c0;
  if (!isW2) { c0 = blockIdx.x * 32; r0 = blockIdx.y * 32; }
  else       { r0 = blockIdx.x * 32; c0 = blockIdx.y * 32; }
  const float* ip = (isW2 ? W2 : W1) + (size_t)l * 1048576;
  ushort* op = (isW2 ? w2t : w1t) + (size_t)l * 1048576;
  int j = threadIdx.x & 31, i0 = threadIdx.x >> 5;
#pragma unroll
  for (int p = 0; p < 4; p++) {
    int r = r0 + i0 + p * 8;
    t[i0 + p * 8][j] = ip[(size_t)r * C + c0 + j];
  }
  __syncthreads();
#pragma unroll
  for (int p = 0; p < 4; p++) {
    int cc = c0 + i0 + p * 8;
    op[(size_t)cc * R + r0 + j] = f2bf(t[j][i0 + p * 8]);
  }
}

// ---------------- bf16 MFMA GEMM, 2-phase pipelined (counted vmcnt) -------
template <int BM, int BN, int RELU, int OUTBF, int NTV, int LGP, int SPLITK,
          int SWZ>
__global__ __launch_bounds__(256) void gemm_mfma(
    const ushort* __restrict__ A, const ushort* __restrict__ Bw,
    const float* __restrict__ bias, float* __restrict__ Cf,
    ushort* __restrict__ Cb, ushort* __restrict__ vt, int M, int N, int K) {
  constexpr int WM = BM / 64;
  constexpr int WN = 4 / WM;
  constexpr int W = BN / WN;
  constexpr int AF = 4;
  constexpr int BF = W / 16;
  constexpr int GA = BM * 8;
  constexpr int GPT = (BM + BN) * 8 / 256;
  __shared__ __align__(16) ushort lds_s[2][(BM + BN) * 64];
  int bn, bm;
  if (SWZ == 1) {
    int nwg = gridDim.x * gridDim.y;
    int wg = blockIdx.y * gridDim.x + blockIdx.x;
    int cpx = nwg >> 3;
    int swz = (wg & 7) * cpx + (wg >> 3);
    bn = (swz % gridDim.x) * BN;
    bm = (swz / gridDim.x) * BM;
  } else {
    bn = blockIdx.x * BN;
    bm = blockIdx.y * BM;
  }
  int kz = (SPLITK > 1) ? blockIdx.z : 0;
  int Keff = K / SPLITK;
  int kbase = kz * Keff;
  int tid = threadIdx.x, lane = tid & 63, w = tid >> 6;
  int wm = w / WN, wn = w % WN;
  int c = lane & 15, g16 = lane >> 4;
  f32x4 acc[AF][BF] = {};

  auto STAGE = [&](int k0, int bufi) {
#pragma unroll
    for (int i = 0; i < GPT; i++) {
      int gidx = i * 256 + tid;
      int gbase = (i * 4 + w) * 64;
      const ushort* src;
      if (gidx < GA) {
        int row = gidx >> 3, dg = gidx & 7;
        src = A + (size_t)(bm + row) * K + kbase + k0 + ((dg ^ (row & 7)) << 3);
      } else {
        int bidx = gidx - GA;
        int row = bidx >> 3, dg = bidx & 7;
        src = Bw + (size_t)(bn + row) * K + kbase + k0 + ((dg ^ (row & 7)) << 3);
      }
      gload_lds16(src, (void*)((char*)(&lds_s[bufi][0]) + gbase * 16));
    }
  };

  int nk = Keff >> 6;
  STAGE(0, 0);
  for (int kt = 0; kt < nk; kt++) {
    int cur = kt & 1;
    if (kt + 1 < nk) {
      STAGE((kt + 1) << 6, cur ^ 1);
      asm volatile("s_waitcnt vmcnt(%0)" ::"n"(GPT) : "memory");
    } else {
      asm volatile("s_waitcnt vmcnt(0)" ::: "memory");
    }
    __builtin_amdgcn_s_barrier();
    __builtin_amdgcn_sched_barrier(0);
    const ushort* Alds = &lds_s[cur][0];
    const ushort* Blds = &lds_s[cur][BM * 64];
#pragma unroll
    for (int ks = 0; ks < 2; ks++) {
      int g = ks * 4 + g16;
      bf16x8 a[AF], b[BF];
#pragma unroll
      for (int i = 0; i < AF; i++) {
        int R = wm * 64 + i * 16 + c;
        a[i] = *(const bf16x8*)(Alds + R * 64 + ((g ^ (R & 7)) << 3));
      }
#pragma unroll
      for (int j = 0; j < BF; j++) {
        int Rb = wn * W + j * 16 + c;
        b[j] = *(const bf16x8*)(Blds + Rb * 64 + ((g ^ (Rb & 7)) << 3));
      }
#pragma unroll
      for (int i = 0; i < AF; i++)
#pragma unroll
        for (int j = 0; j < BF; j++)
          acc[i][j] = __builtin_amdgcn_mfma_f32_16x16x32_bf16(a[i], b[j],
                                                              acc[i][j], 0, 0, 0);
    }
    __builtin_amdgcn_sched_barrier(0);
    __builtin_amdgcn_s_barrier();
  }
  int rb = g16 * 4;
#pragma unroll
  for (int j = 0; j < BF; j++) {
    int col = bn + wn * W + j * 16 + c;
    float bv = (SPLITK > 1 && kz != 0) ? 0.0f : bias[col];
    int cc = LGP ? (col & ((1 << LGP) - 1)) : col;
    int lp = LGP ? (col >> LGP) : 0;
    if (NTV > 0 && cc >= NTV) {
      int hh = (cc - NTV) >> 6, dv = col & 63;
      ushort* vtl = vt + (size_t)lp * 2097152;
#pragma unroll
      for (int i = 0; i < AF; i++) {
        int row = bm + wm * 64 + i * 16 + rb;
        int b_ = row >> 9, s_ = row & 511;
        ushort4 o4;
        o4.x = f2bf(acc[i][j][0] + bv);
        o4.y = f2bf(acc[i][j][1] + bv);
        o4.z = f2bf(acc[i][j][2] + bv);
        o4.w = f2bf(acc[i][j][3] + bv);
        *reinterpret_cast<ushort4*>(
            vtl + ((size_t)(b_ * 8 + hh) * 64 + dv) * 512 + s_) = o4;
      }
    } else {
#pragma unroll
      for (int i = 0; i < AF; i++) {
#pragma unroll
        for (int qq = 0; qq < 4; qq++) {
          int row = bm + wm * 64 + i * 16 + rb + qq;
          float v = acc[i][j][qq] + bv;
          if (RELU) v = fmaxf(v, 0.0f);
          if (OUTBF)
            Cb[(size_t)kz * M * N + (size_t)row * N + col] = f2bf(v);
          else
            Cf[(size_t)kz * M * N + (size_t)row * N + col] = v;
        }
      }
    }
  }
}

// ---------------- MFMA flash attention (swapped QK^T, lane-local softmax) --
template <int MASKED, int NW>
__global__ __launch_bounds__(NW * 64) void attn_mfma(
    const ushort* __restrict__ q, int qstr, const ushort* __restrict__ k,
    int kstr, const ushort* __restrict__ vt, ushort* __restrict__ out) {
  __shared__ __align__(16) char lds[32768 + NW * 2048];
  int h = blockIdx.y, b = blockIdx.z;
  int qc = blockIdx.x;
  if (MASKED && (b & 4)) qc = gridDim.x - 1 - qc;  // causal balance flip
  int q0 = qc * (NW * 16);
  int tid = threadIdx.x, lane = tid & 63, w = tid >> 6;
  int c = lane & 15, g16 = lane >> 4, rb = g16 * 4;

  bf16x8 qa[2];
#pragma unroll
  for (int ks = 0; ks < 2; ks++)
    qa[ks] = *(const bf16x8*)(q + (size_t)(b * SS + q0 + 16 * w + c) * qstr +
                              h * 64 + ks * 32 + g16 * 8);
  f32x4 o[4] = {};
  float mq = -1e30f, lq = 0.f;

  int nt = MASKED ? (q0 >> 6) + 1 : 8;
  int pbase = 32768 + w * 2048;

  constexpr int GPTK = 512 / (NW * 64);
  bf16x8 rk[GPTK], rv[GPTK];
  const ushort* vbase = vt + ((size_t)(b * 8 + h) * 64) * 512;
  auto LOADT = [&](int kv0) {
#pragma unroll
    for (int i = 0; i < GPTK; i++) {
      int idx = tid + i * (NW * 64);
      int row = idx >> 3, gw = idx & 7;
      rk[i] = *(const bf16x8*)(k + (size_t)(b * SS + kv0 + row) * kstr +
                               h * 64 + gw * 8);
      rv[i] = *(const bf16x8*)(vbase + (size_t)row * 512 + kv0 + gw * 8);
    }
  };
  auto WRT = [&](int bufi) {
    char* p = lds + bufi * 16384;
#pragma unroll
    for (int i = 0; i < GPTK; i++) {
      int idx = tid + i * (NW * 64);
      int row = idx >> 3, gw = idx & 7;
      *(bf16x8*)(p + row * 128 + ((gw ^ (row & 7)) << 4)) = rk[i];
      *(bf16x8*)(p + 8192 + row * 128 + ((gw ^ (row & 7)) << 4)) = rv[i];
    }
  };
  LOADT(0);
  WRT(0);
  for (int t = 0; t < nt; t++) {
    if (t + 1 < nt) LOADT((t + 1) * 64);
    __syncthreads();
    char* kb_ = lds + (t & 1) * 16384;
    char* vb_ = kb_ + 8192;
    f32x4 sp[4] = {};
    __builtin_amdgcn_s_setprio(1);
#pragma unroll
    for (int ks = 0; ks < 2; ks++) {
      int g = ks * 4 + g16;
#pragma unroll
      for (int f = 0; f < 4; f++) {
        int row = f * 16 + c;
        bf16x8 k8 = *(bf16x8*)(kb_ + row * 128 + ((g ^ (row & 7)) << 4));
        sp[f] = __builtin_amdgcn_mfma_f32_16x16x32_bf16(k8, qa[ks], sp[f], 0, 0, 0);
      }
    }
    __builtin_amdgcn_s_setprio(0);
    if (MASKED && t == nt - 1) {
      int ql = 16 * w + c;
#pragma unroll
      for (int f = 0; f < 4; f++)
#pragma unroll
        for (int j = 0; j < 4; j++)
          sp[f][j] += (f * 16 + rb + j) <= ql ? 0.0f : -1e9f;
    }
    float tmax = -1e30f;
#pragma unroll
    for (int f = 0; f < 4; f++)
#pragma unroll
      for (int j = 0; j < 4; j++) tmax = fmaxf(tmax, sp[f][j]);
    tmax = fmaxf(tmax, __shfl_xor(tmax, 16));
    tmax = fmaxf(tmax, __shfl_xor(tmax, 32));
    if (!__all(tmax <= mq + 4.0f)) {
      float mn = fmaxf(mq, tmax);
      float scq = exp2f(mq - mn);
      mq = mn;
      lq *= scq;
      int sb = lane & 48;
#pragma unroll
      for (int j = 0; j < 4; j++) {
        float scj = __shfl(scq, sb | (rb + j));
        o[0][j] *= scj; o[1][j] *= scj; o[2][j] *= scj; o[3][j] *= scj;
      }
    }
    float psum = 0.f;
#pragma unroll
    for (int f = 0; f < 4; f++)
#pragma unroll
      for (int j = 0; j < 4; j++) {
        float pv = exp2f(sp[f][j] - mq);
        sp[f][j] = pv;
        psum += pv;
      }
    psum += __shfl_xor(psum, 16);
    psum += __shfl_xor(psum, 32);
    lq += psum;
#pragma unroll
    for (int f = 0; f < 4; f++) {
      int kv0 = f * 16 + rb;
      ushort4 pk;
      pk.x = f2bf(sp[f][0]); pk.y = f2bf(sp[f][1]);
      pk.z = f2bf(sp[f][2]); pk.w = f2bf(sp[f][3]);
      int gg = kv0 >> 3, off = (kv0 & 7) * 2;
      *(ushort4*)(lds + pbase + c * 128 + ((gg ^ (c & 7)) << 4) + off) = pk;
    }
    __builtin_amdgcn_s_setprio(1);
#pragma unroll
    for (int ks2 = 0; ks2 < 2; ks2++) {
      int g = ks2 * 4 + g16;
      bf16x8 pa = *(bf16x8*)(lds + pbase + c * 128 + ((g ^ (c & 7)) << 4));
#pragma unroll
      for (int f = 0; f < 4; f++) {
        int row = f * 16 + c;
        bf16x8 v8 = *(bf16x8*)(vb_ + row * 128 + ((g ^ (row & 7)) << 4));
        o[f] = __builtin_amdgcn_mfma_f32_16x16x32_bf16(pa, v8, o[f], 0, 0, 0);
      }
    }
    __builtin_amdgcn_s_setprio(0);
    if (t + 1 < nt) WRT((t + 1) & 1);
  }
  float invq = 1.0f / lq;
  int sb = lane & 48;
#pragma unroll
  for (int j = 0; j < 4; j++) {
    float invj = __shfl(invq, sb | (rb + j));
    size_t rowo = (size_t)(b * SS + q0 + 16 * w + rb + j) * 512 + h * 64;
#pragma unroll
    for (int f = 0; f < 4; f++)
      out[rowo + f * 16 + c] = f2bf(o[f][j] * invj);
  }
}

// ---------------- residual add + LayerNorm (bf16 residual, wave/row) ------
// Y2=0: y = bf16 yb.  Y2=2: y = bf16 yb + bf16 yb1 (split-K bf16 partials).
// xf != nullptr (final layer): write fp32 out only; xb store skipped (dead).
template <int Y2>
__global__ __launch_bounds__(256) void add_ln_kernel(
    ushort* __restrict__ xb, const ushort* __restrict__ yb,
    const ushort* __restrict__ yb1, const float* __restrict__ g,
    const float* __restrict__ bta, float* __restrict__ xf) {
  int row = blockIdx.x * 4 + (threadIdx.x >> 6);
  int lane = threadIdx.x & 63;
  int base = row * DDIM + lane * 8;
  bf16x8 xv = *reinterpret_cast<const bf16x8*>(xb + base);
  float v[8];
  bf16x8 yv = *reinterpret_cast<const bf16x8*>(yb + base);
  if (Y2 == 2) {
    bf16x8 y2v = *reinterpret_cast<const bf16x8*>(yb1 + base);
#pragma unroll
    for (int i = 0; i < 8; i++)
      v[i] = bf2f((ushort)xv[i]) + bf2f((ushort)yv[i]) + bf2f((ushort)y2v[i]);
  } else {
#pragma unroll
    for (int i = 0; i < 8; i++)
      v[i] = bf2f((ushort)xv[i]) + bf2f((ushort)yv[i]);
  }
  float s = 0.f;
#pragma unroll
  for (int i = 0; i < 8; i++) s += v[i];
#pragma unroll
  for (int off = 32; off > 0; off >>= 1) s += __shfl_xor(s, off);
  float mean = s * (1.0f / DDIM);
  float t2 = 0.f;
#pragma unroll
  for (int i = 0; i < 8; i++) {
    v[i] -= mean;
    t2 += v[i] * v[i];
  }
#pragma unroll
  for (int off = 32; off > 0; off >>= 1) t2 += __shfl_xor(t2, off);
  float rs = rsqrtf(t2 * (1.0f / DDIM) + EPSV);
  int cidx = lane * 8;
  float4 g0 = *reinterpret_cast<const float4*>(g + cidx);
  float4 g1 = *reinterpret_cast<const float4*>(g + cidx + 4);
  float4 b0 = *reinterpret_cast<const float4*>(bta + cidx);
  float4 b1 = *reinterpret_cast<const float4*>(bta + cidx + 4);
  float o[8];
  o[0] = v[0] * rs * g0.x + b0.x; o[1] = v[1] * rs * g0.y + b0.y;
  o[2] = v[2] * rs * g0.z + b0.z; o[3] = v[3] * rs * g0.w + b0.w;
  o[4] = v[4] * rs * g1.x + b1.x; o[5] = v[5] * rs * g1.y + b1.y;
  o[6] = v[6] * rs * g1.z + b1.z; o[7] = v[7] * rs * g1.w + b1.w;
  if (xf) {
    float4 w0 = {o[0], o[1], o[2], o[3]}, w1 = {o[4], o[5], o[6], o[7]};
    *reinterpret_cast<float4*>(xf + base) = w0;
    *reinterpret_cast<float4*>(xf + base + 4) = w1;
  } else {
    bf16x8 ob;
#pragma unroll
    for (int i = 0; i < 8; i++) ob[i] = (short)f2bf(o[i]);
    *reinterpret_cast<bf16x8*>(xb + base) = ob;
  }
}

// ---------------- orchestration ----------------
extern "C" void kernel_launch(void* const* d_in, const int* in_sizes, int n_in,
                              void* d_out, int out_size, void* d_ws,
                              size_t ws_size, hipStream_t stream) {
  const int* dec = (const int*)d_in[0];
  const float* enc = (const float*)d_in[1];
  const float* emb = (const float*)d_in[4];
  const float* Wq_s = (const float*)d_in[5];
  const float* Wk_s = (const float*)d_in[6];
  const float* Wv_s = (const float*)d_in[7];
  const float* bq_s = (const float*)d_in[8];
  const float* bk_s = (const float*)d_in[9];
  const float* bv_s = (const float*)d_in[10];
  const float* Wq_c = (const float*)d_in[11];
  const float* Wk_c = (const float*)d_in[12];
  const float* Wv_c = (const float*)d_in[13];
  const float* bq_c = (const float*)d_in[14];
  const float* bk_c = (const float*)d_in[15];
  const float* bv_c = (const float*)d_in[16];
  const float* W1 = (const float*)d_in[17];
  const float* b1 = (const float*)d_in[18];
  const float* W2 = (const float*)d_in[19];
  const float* b2 = (const float*)d_in[20];
  const float* ln1_g = (const float*)d_in[21];
  const float* ln1_b = (const float*)d_in[22];
  const float* ln2_g = (const float*)d_in[23];
  const float* ln2_b = (const float*)d_in[24];

  char* ws = (char*)d_ws;
  ushort* wqkv = (ushort*)(ws + 0);
  ushort* wqc = (ushort*)(ws + 9437184ull);
  ushort* wckv = (ushort*)(ws + 12582912ull);
  ushort* w1t = (ushort*)(ws + 18874368ull);
  ushort* w2t = (ushort*)(ws + 31457280ull);
  ushort* encb = (ushort*)(ws + 44040192ull);
  ushort* xb = (ushort*)(ws + 48234496ull);
  ushort* tmpb = (ushort*)(ws + 52428800ull);
  ushort* ff2p = (ushort*)(ws + 56623104ull);   // 2 x 4MB bf16 partials
  ushort* qkvbuf = (ushort*)(ws + 73400320ull);
  ushort* cq = (ushort*)(ws + 73400320ull);
  ushort* ff1b = (ushort*)(ws + 73400320ull);
  ushort* vt = (ushort*)(ws + 85983232ull);
  float* qkvbias = (float*)(ws + 90177536ull);
  float* ckvbias = (float*)(ws + 90214400ull);
  ushort* ckvbuf = (ushort*)(ws + 90238976ull);
  ushort* vtc = (ushort*)(ws + 140570624ull);
  float* cqbias = (float*)(ws + 165736448ull);

  const int M = BB * SS;  // 4096
  dim3 g256(256);

  prep_kernel<<<dim3(2048), g256, 0, stream>>>(dec, emb, enc, bq_s, bk_s, bv_s,
                                               bk_c, bv_c, bq_c, xb, encb,
                                               qkvbias, ckvbias, cqbias);
  wtrans6_kernel<<<dim3(2, 16, 288), g256, 0, stream>>>(
      Wq_s, Wk_s, Wv_s, Wq_c, Wk_c, Wv_c, wqkv, wqc, wckv);
  wtransff_kernel<<<dim3(64, 16, 12), g256, 0, stream>>>(W1, W2, w1t, w2t);

  // ---- hoisted cross K/V; plain block order (both XCD chunkings thrash) ---
  gemm_mfma<128, 128, 0, 1, 512, 10, 1, 0><<<dim3(48, 32), g256, 0, stream>>>(
      encb, wckv, ckvbias, nullptr, ckvbuf, vtc, M, 6144, 512);

  for (int l = 0; l < NLAYER; l++) {
    gemm_mfma<64, 128, 0, 1, 1024, 0, 1, 1><<<dim3(12, 64), g256, 0, stream>>>(
        xb, wqkv + (size_t)l * 786432, qkvbias + l * 1536, nullptr, qkvbuf, vt,
        M, 1536, 512);
    attn_mfma<1, 4><<<dim3(8, 8, 8), g256, 0, stream>>>(
        qkvbuf, 1536, qkvbuf + 512, 1536, vt, tmpb);
    add_ln_kernel<0><<<dim3(M / 4), g256, 0, stream>>>(
        xb, tmpb, nullptr, ln1_g + l * 512, ln1_b + l * 512, nullptr);
    gemm_mfma<64, 128, 0, 1, 0, 0, 1, 1><<<dim3(4, 64), g256, 0, stream>>>(
        xb, wqc + (size_t)l * 262144, cqbias + l * 512, nullptr, cq, nullptr,
        M, 512, 512);
    attn_mfma<0, 8><<<dim3(4, 8, 8), dim3(512), 0, stream>>>(
        cq, 512, ckvbuf + l * 1024, 6144, vtc + (size_t)l * 2097152, tmpb);
    add_ln_kernel<0><<<dim3(M / 4), g256, 0, stream>>>(
        xb, tmpb, nullptr, ln2_g + l * 512, ln2_b + l * 512, nullptr);
    gemm_mfma<128, 128, 1, 1, 0, 0, 1, 1><<<dim3(16, 32), g256, 0, stream>>>(
        xb, w1t + (size_t)l * 1048576, b1 + l * DFFV, nullptr, ff1b, nullptr,
        M, DFFV, 512);
    gemm_mfma<64, 128, 0, 1, 0, 0, 2, 1><<<dim3(4, 64, 2), g256, 0, stream>>>(
        ff1b, w2t + (size_t)l * 1048576, b2 + l * 512, nullptr, ff2p, nullptr,
        M, 512, DFFV);
    add_ln_kernel<2><<<dim3(M / 4), g256, 0, stream>>>(
        xb, ff2p, ff2p + (size_t)M * 512, ln2_g + l * 512, ln2_b + l * 512,
        (l == NLAYER - 1) ? (float*)d_out : nullptr);
  }
}